// Round 3
// baseline (88.396 us; speedup 1.0000x reference)
//
#include <hip/hip_runtime.h>
#include <hip/hip_bf16.h>

#define BATCH 4096
#define DIM   128
#define NT    32   // 4096 / 128 tiles per dimension
// TEMP = 0.25 -> 1/T = 4; 4*log2(e):
#define EXP_SCALE 5.770780163555854f

typedef __bf16 bf16_t;
typedef __bf16 bf16x8 __attribute__((ext_vector_type(8)));
typedef float  f32x4  __attribute__((ext_vector_type(4)));

// ---------------------------------------------------------------------------
// Fused kernel: one 128x128 tile of S = Zi * Zj^T per block (grid 32x32).
// Phase 1: block normalizes its own 128 rows of emb_i and emb_j (fp32 in,
//          bf16 out) straight into LDS.
// Phase 2: bf16 MFMA 16x16x32, K=128 in 4 steps.
// Phase 3: e = exp(4*s); per-lane row/col partials; shfl-reduce rows (each
//          wave's rows are complete); cross-WAVE LDS reduce for columns
//          (each wave only covers 32 of the 128 tile rows — this was the
//          round-2 bug: plain stores overwrote, losing 3/4 of the colsum).
//          Write-once partials pr[tj*B + row], pc[ti*B + col]; diagonal
//          blocks also write pos[k] = S[k][k].
// ---------------------------------------------------------------------------
__global__ __launch_bounds__(256) void fused_kernel(
    const float* __restrict__ emb_i, const float* __restrict__ emb_j,
    float* __restrict__ pr, float* __restrict__ pc, float* __restrict__ pos)
{
    __shared__ __align__(16) bf16_t zi_s[128][136];
    __shared__ __align__(16) bf16_t zj_s[128][136];
    __shared__ float colRed[4][128];

    const int tid = threadIdx.x;
    const int ti = blockIdx.x, tj = blockIdx.y;

    // ---- Phase 1: normalize 128 rows of each input into LDS as bf16 ----
    const int g  = tid >> 4;   // group id 0..15 (= wave*4 + quad)
    const int gl = tid & 15;   // lane in group

#pragma unroll
    for (int m = 0; m < 2; ++m) {
        const float* src = m ? emb_j : emb_i;
        const int rbase = (m ? tj : ti) * 128;
        bf16_t (*dst)[136] = m ? zj_s : zi_s;
#pragma unroll
        for (int it = 0; it < 8; ++it) {
            int row = it * 16 + g;
            const float4* p = (const float4*)(src + (size_t)(rbase + row) * DIM);
            float4 a = p[gl * 2];
            float4 b = p[gl * 2 + 1];
            float ss = a.x*a.x + a.y*a.y + a.z*a.z + a.w*a.w
                     + b.x*b.x + b.y*b.y + b.z*b.z + b.w*b.w;
            ss += __shfl_xor(ss, 1);
            ss += __shfl_xor(ss, 2);
            ss += __shfl_xor(ss, 4);
            ss += __shfl_xor(ss, 8);
            float inv = 1.0f / fmaxf(sqrtf(ss), 1e-12f);
            bf16x8 o;
            o[0] = (bf16_t)(a.x * inv); o[1] = (bf16_t)(a.y * inv);
            o[2] = (bf16_t)(a.z * inv); o[3] = (bf16_t)(a.w * inv);
            o[4] = (bf16_t)(b.x * inv); o[5] = (bf16_t)(b.y * inv);
            o[6] = (bf16_t)(b.z * inv); o[7] = (bf16_t)(b.w * inv);
            *(bf16x8*)&dst[row][gl * 8] = o;
        }
    }
    __syncthreads();

    // ---- Phase 2: MFMA ----
    const int wave = tid >> 6;
    const int lane = tid & 63;
    const int l15  = lane & 15;
    const int quad = lane >> 4;

    const f32x4 vzero = {0.f, 0.f, 0.f, 0.f};
    f32x4 acc[2][8];
#pragma unroll
    for (int rt = 0; rt < 2; ++rt)
#pragma unroll
        for (int ct = 0; ct < 8; ++ct) acc[rt][ct] = vzero;

#pragma unroll
    for (int ks = 0; ks < 4; ++ks) {
        int k0 = ks * 32 + quad * 8;
        bf16x8 afrag[2], bfrag[8];
#pragma unroll
        for (int rt = 0; rt < 2; ++rt)
            afrag[rt] = *(const bf16x8*)&zi_s[(wave * 2 + rt) * 16 + l15][k0];
#pragma unroll
        for (int ct = 0; ct < 8; ++ct)
            bfrag[ct] = *(const bf16x8*)&zj_s[ct * 16 + l15][k0];
#pragma unroll
        for (int rt = 0; rt < 2; ++rt)
#pragma unroll
            for (int ct = 0; ct < 8; ++ct)
                acc[rt][ct] = __builtin_amdgcn_mfma_f32_16x16x32_bf16(
                    afrag[rt], bfrag[ct], acc[rt][ct], 0, 0, 0);
    }

    // ---- Phase 3a: diagonal blocks extract pos[k] = S[k][k] ----
    if (ti == tj) {
#pragma unroll
        for (int rt = 0; rt < 2; ++rt)
#pragma unroll
            for (int ct = 0; ct < 8; ++ct)
#pragma unroll
                for (int r = 0; r < 4; ++r) {
                    int rr = (wave * 2 + rt) * 16 + quad * 4 + r;
                    int cc = ct * 16 + l15;
                    if (rr == cc) pos[ti * 128 + rr] = acc[rt][ct][r];
                }
    }

    // ---- Phase 3b: exp and partial sums ----
    float rowPart[2][4] = {{0.f, 0.f, 0.f, 0.f}, {0.f, 0.f, 0.f, 0.f}};
    float colPart[8]    = {0.f, 0.f, 0.f, 0.f, 0.f, 0.f, 0.f, 0.f};
#pragma unroll
    for (int rt = 0; rt < 2; ++rt)
#pragma unroll
        for (int ct = 0; ct < 8; ++ct)
#pragma unroll
            for (int r = 0; r < 4; ++r) {
                float e = exp2f(acc[rt][ct][r] * EXP_SCALE);
                rowPart[rt][r] += e;   // row = (wave*2+rt)*16 + quad*4 + r
                colPart[ct]    += e;   // col = ct*16 + l15
            }

    // Row sums: each wave's rows see all 128 columns (ct=0..7, l15=0..15),
    // so a 16-lane shfl reduce completes the row partial for this tile.
#pragma unroll
    for (int rt = 0; rt < 2; ++rt)
#pragma unroll
        for (int r = 0; r < 4; ++r) {
            float v = rowPart[rt][r];
            v += __shfl_xor(v, 1);
            v += __shfl_xor(v, 2);
            v += __shfl_xor(v, 4);
            v += __shfl_xor(v, 8);
            if (l15 == 0) {
                int grow = ti * 128 + (wave * 2 + rt) * 16 + quad * 4 + r;
                pr[tj * BATCH + grow] = v;
            }
        }

    // Col sums: a wave only covers its own 32 rows of the tile, so after the
    // quad shfl-reduce we must also reduce ACROSS the 4 waves (via LDS).
#pragma unroll
    for (int ct = 0; ct < 8; ++ct) {
        float v = colPart[ct];
        v += __shfl_xor(v, 16);
        v += __shfl_xor(v, 32);
        if (quad == 0) colRed[wave][ct * 16 + l15] = v;
    }
    __syncthreads();
    if (tid < 128) {
        float s = colRed[0][tid] + colRed[1][tid] + colRed[2][tid] + colRed[3][tid];
        pc[ti * BATCH + tj * 128 + tid] = s;
    }
}

// ---------------------------------------------------------------------------
// Finalize: rowDenom_k = sum_tj pr[tj][k]; colDenom_c = sum_ti pc[ti][c];
// loss = (1/2B) * sum_k [log rowDenom_k + log colDenom_k - 8*pos_k].
// ---------------------------------------------------------------------------
__global__ __launch_bounds__(1024) void finalize_kernel(
    const float* __restrict__ pr, const float* __restrict__ pc,
    const float* __restrict__ pos, float* __restrict__ out)
{
    int tid = threadIdx.x;
    float acc = 0.f;
#pragma unroll
    for (int it = 0; it < 4; ++it) {
        int k = it * 1024 + tid;
        float sR = 0.f, sC = 0.f;
#pragma unroll
        for (int t = 0; t < NT; ++t) {
            sR += pr[t * BATCH + k];
            sC += pc[t * BATCH + k];
        }
        acc += logf(sR) + logf(sC) - 8.0f * pos[k];
    }
#pragma unroll
    for (int m = 1; m < 64; m <<= 1) acc += __shfl_xor(acc, m);
    __shared__ float red[16];
    if ((tid & 63) == 0) red[tid >> 6] = acc;
    __syncthreads();
    if (tid == 0) {
        float s = 0.f;
#pragma unroll
        for (int w = 0; w < 16; ++w) s += red[w];
        out[0] = s * (1.0f / (2.0f * BATCH));
    }
}

extern "C" void kernel_launch(void* const* d_in, const int* in_sizes, int n_in,
                              void* d_out, int out_size, void* d_ws, size_t ws_size,
                              hipStream_t stream) {
    const float* emb_i = (const float*)d_in[0];
    const float* emb_j = (const float*)d_in[1];
    float* out = (float*)d_out;

    char* ws = (char*)d_ws;
    float* pr  = (float*)(ws);                                  // 512 KB
    float* pc  = (float*)(ws + (size_t)NT * BATCH * 4);         // 512 KB
    float* pos = (float*)(ws + (size_t)2 * NT * BATCH * 4);     // 16 KB

    fused_kernel<<<dim3(NT, NT), 256, 0, stream>>>(emb_i, emb_j, pr, pc, pos);
    finalize_kernel<<<1, 1024, 0, stream>>>(pr, pc, pos, out);
}

// Round 4
// 74.602 us; speedup vs baseline: 1.1849x; 1.1849x over previous
//
#include <hip/hip_runtime.h>
#include <hip/hip_bf16.h>

#define BATCH 4096
#define DIM   128
#define NT    32   // 4096 / 128 tiles per dimension
// TEMP = 0.25 -> 1/T = 4; 4*log2(e):
#define EXP_SCALE 5.770780163555854f

typedef __bf16 bf16_t;
typedef __bf16 bf16x8 __attribute__((ext_vector_type(8)));
typedef float  f32x4  __attribute__((ext_vector_type(4)));

// ---------------------------------------------------------------------------
// Kernel A: per row k, normalize emb_i[k] and emb_j[k] (fp32 math), write
// bf16 z_i, z_j to workspace, pos[k] = cos-sim in fp32. One wave per row.
// Blocks 0..15 additionally zero rowDenom/colDenom (16 blocks x 256 thr x 4
// floats = 16384), replacing the separate memset dispatch.
// ---------------------------------------------------------------------------
__global__ __launch_bounds__(256) void normalize_kernel(
    const float* __restrict__ emb_i, const float* __restrict__ emb_j,
    bf16_t* __restrict__ zi, bf16_t* __restrict__ zj, float* __restrict__ pos,
    float* __restrict__ denoms /* rowDenom(4096) ++ colDenom(4096) */)
{
    if (blockIdx.x < 16) {
        int idx = (blockIdx.x * 256 + threadIdx.x) * 4;
        *(float4*)&denoms[idx] = make_float4(0.f, 0.f, 0.f, 0.f);
    }

    int wave = threadIdx.x >> 6;
    int lane = threadIdx.x & 63;
    int k = blockIdx.x * 4 + wave;

    const float2* ei = (const float2*)(emb_i + (size_t)k * DIM);
    const float2* ej = (const float2*)(emb_j + (size_t)k * DIM);
    float2 a = ei[lane];
    float2 b = ej[lane];

    float sii = a.x * a.x + a.y * a.y;
    float sjj = b.x * b.x + b.y * b.y;
    float sij = a.x * b.x + a.y * b.y;
#pragma unroll
    for (int m = 1; m < 64; m <<= 1) {
        sii += __shfl_xor(sii, m);
        sjj += __shfl_xor(sjj, m);
        sij += __shfl_xor(sij, m);
    }
    float inv_i = 1.0f / fmaxf(sqrtf(sii), 1e-12f);
    float inv_j = 1.0f / fmaxf(sqrtf(sjj), 1e-12f);

    struct bf16_2 { bf16_t x, y; };
    bf16_2 pi, pj;
    pi.x = (bf16_t)(a.x * inv_i);  pi.y = (bf16_t)(a.y * inv_i);
    pj.x = (bf16_t)(b.x * inv_j);  pj.y = (bf16_t)(b.y * inv_j);
    ((bf16_2*)(zi + (size_t)k * DIM))[lane] = pi;
    ((bf16_2*)(zj + (size_t)k * DIM))[lane] = pj;

    if (lane == 0) pos[k] = sij * inv_i * inv_j;
}

// ---------------------------------------------------------------------------
// Kernel B: 128x128 tile of S = Zi * Zj^T per block (grid 32x32).
// bf16 MFMA 16x16x32, K=128 in 4 steps. Epilogue: e = exp(4*s); row partials
// complete within a wave (16-lane shfl reduce) -> 1 atomic per row; col
// partials need cross-wave LDS reduce (each wave covers only 32 tile rows)
// -> 128 atomics per block. Denominators are pre-zeroed by kernel A.
// LDS rows padded 128->136 elems (row stride 272 B = 68 banks -> only free
// 2-way conflicts; 16B alignment preserved for b128 access).
// ---------------------------------------------------------------------------
__global__ __launch_bounds__(256) void gemm_exp_kernel(
    const bf16_t* __restrict__ zi, const bf16_t* __restrict__ zj,
    float* __restrict__ rowDenom, float* __restrict__ colDenom)
{
    __shared__ __align__(16) bf16_t zi_s[128][136];
    __shared__ __align__(16) bf16_t zj_s[128][136];
    __shared__ float colRed[4][128];

    const int tid = threadIdx.x;
    const int ti = blockIdx.x, tj = blockIdx.y;

    // Stage 128x128 bf16 of each matrix: 2048 16B-chunks / matrix, 8 iters.
#pragma unroll
    for (int it = 0; it < 8; ++it) {
        int c = it * 256 + tid;
        int row = c >> 4;          // 16 chunks per row
        int col = (c & 15) << 3;   // 8 bf16 per chunk
        *(uint4*)&zi_s[row][col] =
            *(const uint4*)(zi + ((size_t)(ti * 128 + row)) * DIM + col);
        *(uint4*)&zj_s[row][col] =
            *(const uint4*)(zj + ((size_t)(tj * 128 + row)) * DIM + col);
    }
    __syncthreads();

    const int wave = tid >> 6;
    const int lane = tid & 63;
    const int l15  = lane & 15;
    const int quad = lane >> 4;

    const f32x4 vzero = {0.f, 0.f, 0.f, 0.f};
    f32x4 acc[2][8];
#pragma unroll
    for (int rt = 0; rt < 2; ++rt)
#pragma unroll
        for (int ct = 0; ct < 8; ++ct) acc[rt][ct] = vzero;

#pragma unroll
    for (int ks = 0; ks < 4; ++ks) {
        int k0 = ks * 32 + quad * 8;
        bf16x8 afrag[2], bfrag[8];
#pragma unroll
        for (int rt = 0; rt < 2; ++rt)
            afrag[rt] = *(const bf16x8*)&zi_s[(wave * 2 + rt) * 16 + l15][k0];
#pragma unroll
        for (int ct = 0; ct < 8; ++ct)
            bfrag[ct] = *(const bf16x8*)&zj_s[ct * 16 + l15][k0];
#pragma unroll
        for (int rt = 0; rt < 2; ++rt)
#pragma unroll
            for (int ct = 0; ct < 8; ++ct)
                acc[rt][ct] = __builtin_amdgcn_mfma_f32_16x16x32_bf16(
                    afrag[rt], bfrag[ct], acc[rt][ct], 0, 0, 0);
    }

    // Epilogue: exp and partial sums.
    float rowPart[2][4] = {{0.f, 0.f, 0.f, 0.f}, {0.f, 0.f, 0.f, 0.f}};
    float colPart[8]    = {0.f, 0.f, 0.f, 0.f, 0.f, 0.f, 0.f, 0.f};
#pragma unroll
    for (int rt = 0; rt < 2; ++rt)
#pragma unroll
        for (int ct = 0; ct < 8; ++ct)
#pragma unroll
            for (int r = 0; r < 4; ++r) {
                float e = exp2f(acc[rt][ct][r] * EXP_SCALE);
                rowPart[rt][r] += e;   // row = (wave*2+rt)*16 + quad*4 + r
                colPart[ct]    += e;   // col = ct*16 + l15
            }

    // Row sums: each wave's rows see all 128 tile columns; 16-lane shfl
    // reduce completes them. One atomic per row per block.
#pragma unroll
    for (int rt = 0; rt < 2; ++rt)
#pragma unroll
        for (int r = 0; r < 4; ++r) {
            float v = rowPart[rt][r];
            v += __shfl_xor(v, 1);
            v += __shfl_xor(v, 2);
            v += __shfl_xor(v, 4);
            v += __shfl_xor(v, 8);
            if (l15 == 0) {
                int grow = ti * 128 + (wave * 2 + rt) * 16 + quad * 4 + r;
                atomicAdd(&rowDenom[grow], v);
            }
        }

    // Col sums: quad shfl-reduce, then cross-wave LDS reduce, then one
    // coalesced atomic per column per block.
#pragma unroll
    for (int ct = 0; ct < 8; ++ct) {
        float v = colPart[ct];
        v += __shfl_xor(v, 16);
        v += __shfl_xor(v, 32);
        if (quad == 0) colRed[wave][ct * 16 + l15] = v;
    }
    __syncthreads();
    if (tid < 128) {
        float s = colRed[0][tid] + colRed[1][tid] + colRed[2][tid] + colRed[3][tid];
        atomicAdd(&colDenom[tj * 128 + tid], s);
    }
}

// ---------------------------------------------------------------------------
// Kernel C: loss = (1/2B) * sum_k [log rowDenom_k + log colDenom_k - 8*pos_k]
// Only 48 KB of reads -> single block is fine.
// ---------------------------------------------------------------------------
__global__ __launch_bounds__(256) void finalize_kernel(
    const float* __restrict__ denoms, const float* __restrict__ pos,
    float* __restrict__ out)
{
    const float* rowDenom = denoms;
    const float* colDenom = denoms + BATCH;
    int tid = threadIdx.x;
    float acc = 0.f;
#pragma unroll
    for (int it = 0; it < 16; ++it) {
        int k = it * 256 + tid;
        acc += logf(rowDenom[k]) + logf(colDenom[k]) - 8.0f * pos[k];
    }
#pragma unroll
    for (int m = 1; m < 64; m <<= 1) acc += __shfl_xor(acc, m);
    __shared__ float red[4];
    if ((tid & 63) == 0) red[tid >> 6] = acc;
    __syncthreads();
    if (tid == 0)
        out[0] = (red[0] + red[1] + red[2] + red[3]) * (1.0f / (2.0f * BATCH));
}

extern "C" void kernel_launch(void* const* d_in, const int* in_sizes, int n_in,
                              void* d_out, int out_size, void* d_ws, size_t ws_size,
                              hipStream_t stream) {
    const float* emb_i = (const float*)d_in[0];
    const float* emb_j = (const float*)d_in[1];
    float* out = (float*)d_out;

    char* ws = (char*)d_ws;
    bf16_t* zi     = (bf16_t*)(ws);                 // 1 MB
    bf16_t* zj     = (bf16_t*)(ws + (1u << 20));    // 1 MB
    float*  denoms = (float*)(ws + (2u << 20));     // 32 KB (row ++ col)
    float*  pos    = denoms + 2 * BATCH;            // 16 KB

    normalize_kernel<<<BATCH / 4, 256, 0, stream>>>(emb_i, emb_j, zi, zj, pos, denoms);
    gemm_exp_kernel<<<dim3(NT, NT), 256, 0, stream>>>(zi, zj, denoms, denoms + BATCH);
    finalize_kernel<<<1, 256, 0, stream>>>(denoms, pos, out);
}